// Round 6
// baseline (95.320 us; speedup 1.0000x reference)
//
#include <hip/hip_runtime.h>

// SSIM loss, fully fused (R6): packed-f32x2 compute core (R5) with
// conflict-free LDS staging: each thread owns BOTH tensors for a 2-pixel
// slice (6x global_load_dwordx2 -> channel means -> one contiguous
// ds_write_b128 {P0,T0,P1,T1}). Reads are ds_read_b64 at 8B lane stride
// (2-way, free). 12-slot packed register ring, shift-by-2, 2 rows/barrier.

typedef float f32x2 __attribute__((ext_vector_type(2)));

constexpr int KW   = 11;
constexpr int HALF = 5;
constexpr int IMG_H = 512;
constexpr int IMG_W = 512;
constexpr int NB   = 32;
constexpr int NCH  = 3;
constexpr int TR   = 32;                  // strip height
constexpr int BT   = 512;                 // threads = cols
constexpr int LW   = IMG_W + 16;          // 528: 8-slot halo each side
constexpr int NP   = (TR + 2 * HALF) / 2; // 21 row-pairs

__global__ __launch_bounds__(BT)
void ssim_fused(const float* __restrict__ pred,
                const float* __restrict__ targ,
                const float* __restrict__ win,
                float* __restrict__ out)
{
    __shared__ f32x2 lds[2][2][LW];   // [buf][row-of-pair][col+8] = (P, T)
    __shared__ float red[BT / 64];

    const int tid  = threadIdx.x;
    const int nrow = IMG_H / TR;             // 16
    const int img  = blockIdx.x / nrow;
    const int R0   = (blockIdx.x % nrow) * TR;

    // zero the 8-slot halos of all 4 row-slots (both buffers), once
    if (tid < 64) {
        int b = tid & 1, r = (tid >> 1) & 1, s = (tid >> 2) & 1, k = tid >> 3;
        int idx = s ? (IMG_W + 8 + k) : k;
        lds[b][r][idx] = (f32x2)(0.f, 0.f);
    }

    // exact 1-D gaussian (symmetric, 6 unique) from the passed 2-D window
    float gs[6];
    {
        float g5 = sqrtf(win[HALF * KW + HALF]);
        #pragma unroll
        for (int j = 0; j < 6; ++j) gs[j] = win[HALF * KW + j] / g5;
    }
    auto W = [&](int j) { return gs[j <= 5 ? j : 10 - j]; };  // j static

    const size_t ims = (size_t)IMG_H * IMG_W;
    // load role: 2-pixel slice (hpos) of one row of the pair, BOTH tensors
    const int hpos    = tid & 255;           // 256 float2 slices per row
    const int row_off = tid >> 8;            // row within pair (wave-uniform)
    const float* pb = pred + (size_t)img * NCH * ims + (size_t)hpos * 2;
    const float* tb = targ + (size_t)img * NCH * ims + (size_t)hpos * 2;
    const float inv3 = 1.0f / 3.0f;

    float2 p0, p1, p2, t0, t1, t2;
    auto issue = [&](int pair) {
        int r = R0 - HALF + 2 * pair + row_off;
        if (r >= 0 && r < IMG_H) {
            const float* pr = pb + (size_t)r * IMG_W;
            const float* tr = tb + (size_t)r * IMG_W;
            p0 = *(const float2*)(pr);
            p1 = *(const float2*)(pr + ims);
            p2 = *(const float2*)(pr + 2 * ims);
            t0 = *(const float2*)(tr);
            t1 = *(const float2*)(tr + ims);
            t2 = *(const float2*)(tr + 2 * ims);
        } else {
            p0 = make_float2(0.f, 0.f);
            p1 = p0; p2 = p0; t0 = p0; t1 = p0; t2 = p0;
        }
    };
    auto commit = [&](int pair) {
        float4 m;                             // {P0, T0, P1, T1}
        m.x = (p0.x + p1.x + p2.x) * inv3;
        m.y = (t0.x + t1.x + t2.x) * inv3;
        m.z = (p0.y + p1.y + p2.y) * inv3;
        m.w = (t0.y + t1.y + t2.y) * inv3;
        *(float4*)&lds[pair & 1][row_off][8 + 2 * hpos] = m;  // b128, stride-1
    };

    // 12-slot vertical ring, plane-packed (statically indexed everywhere)
    f32x2 rMU[12], rSQ[12];   // (hconv P, hconv T), (hconv P^2, hconv T^2)
    float rPT[12];            // hconv P*T
    #pragma unroll
    for (int k = 0; k < 12; ++k) {
        rMU[k] = (f32x2)(0.f, 0.f); rSQ[k] = (f32x2)(0.f, 0.f); rPT[k] = 0.f;
    }

    const float C1 = 1e-4f, C2 = 9e-4f;
    const int c = tid;                       // output column
    float acc = 0.f;

    issue(0);
    for (int i = 0; i < NP; ++i) {
        commit(i);
        if (i + 1 < NP) issue(i + 1);   // next-pair loads in flight over compute
        __syncthreads();
        const int buf = i & 1;

        // horizontal 11-tap for the 2 staged rows -> ring slots 10, 11
        #pragma unroll
        for (int rr = 0; rr < 2; ++rr) {
            f32x2 mu = (f32x2)(0.f, 0.f), sq = (f32x2)(0.f, 0.f);
            float spt = 0.f;
            #pragma unroll
            for (int j = 0; j < KW; ++j) {
                const float w = W(j);
                f32x2 v = lds[buf][rr][c + 3 + j];   // (p,t), ds_read_b64
                mu  += v * w;                         // v_pk_fma_f32
                sq  += (v * v) * w;                   // v_pk_mul + v_pk_fma
                spt += (v.x * v.y) * w;               // v_mul + v_fma
            }
            rMU[10 + rr] = mu; rSQ[10 + rr] = sq; rPT[10 + rr] = spt;
        }

        // vertical 11-tap + SSIM for 2 output rows
        if (i >= 5) {
            #pragma unroll
            for (int off = 0; off < 2; ++off) {
                f32x2 m = (f32x2)(0.f, 0.f), e = (f32x2)(0.f, 0.f);
                float ept = 0.f;
                #pragma unroll
                for (int k = 0; k < KW; ++k) {
                    const float w = W(k);
                    m += rMU[off + k] * w;            // v_pk_fma (mu1,mu2)
                    e += rSQ[off + k] * w;            // v_pk_fma (eP2,eT2)
                    ept += rPT[off + k] * w;          // v_fma
                }
                f32x2 msq = m * m;                    // (m11, m22)
                float m12 = m.x * m.y;
                f32x2 s = e - msq;                    // (s1, s2)
                float s12 = ept - m12;
                float num = (2.f * m12 + C1) * (2.f * s12 + C2);
                float den = (msq.x + msq.y + C1) * (s.x + s.y + C2);
                acc += 1.f - num * __builtin_amdgcn_rcpf(den);
            }
        }

        // shift ring by 2 (pk_movs for the packed arrays)
        #pragma unroll
        for (int k = 0; k < 10; ++k) {
            rMU[k] = rMU[k + 2]; rSQ[k] = rSQ[k + 2]; rPT[k] = rPT[k + 2];
        }
    }

    // block reduction
    #pragma unroll
    for (int off = 32; off >= 1; off >>= 1)
        acc += __shfl_down(acc, off, 64);
    if ((tid & 63) == 0) red[tid >> 6] = acc;
    __syncthreads();
    if (tid == 0) {
        float s = 0.f;
        #pragma unroll
        for (int w = 0; w < BT / 64; ++w) s += red[w];
        atomicAdd(out, s * (1.0f / ((float)NB * IMG_H * IMG_W)));
    }
}

extern "C" void kernel_launch(void* const* d_in, const int* in_sizes, int n_in,
                              void* d_out, int out_size, void* d_ws, size_t ws_size,
                              hipStream_t stream) {
    const float* pred = (const float*)d_in[0];
    const float* targ = (const float*)d_in[1];
    const float* win  = (const float*)d_in[2];
    float* out = (float*)d_out;

    hipMemsetAsync(out, 0, sizeof(float), stream);

    dim3 grid(NB * (IMG_H / TR));   // 512 blocks, 8 waves each
    ssim_fused<<<grid, BT, 0, stream>>>(pred, targ, win, out);
}

// Round 7
// 90.676 us; speedup vs baseline: 1.0512x; 1.0512x over previous
//
#include <hip/hip_runtime.h>

// SSIM loss, fully fused (R7): R6's packed-f32x2 core with
//  (a) issue(i+1) moved AFTER __syncthreads so the compiler's
//      vmcnt(0)-before-barrier drain no longer kills the prefetch, and
//  (b) even/odd-tap split accumulators in both conv phases (2x ILP).
// Conflict-free staging: each thread owns both tensors for a 2-pixel slice,
// one contiguous ds_write_b128 {P0,T0,P1,T1}; reads ds_read_b64 (2-way, free).

typedef float f32x2 __attribute__((ext_vector_type(2)));

constexpr int KW   = 11;
constexpr int HALF = 5;
constexpr int IMG_H = 512;
constexpr int IMG_W = 512;
constexpr int NB   = 32;
constexpr int NCH  = 3;
constexpr int TR   = 32;                  // strip height
constexpr int BT   = 512;                 // threads = cols
constexpr int LW   = IMG_W + 16;          // 528: 8-slot halo each side
constexpr int NP   = (TR + 2 * HALF) / 2; // 21 row-pairs

__global__ __launch_bounds__(BT)
void ssim_fused(const float* __restrict__ pred,
                const float* __restrict__ targ,
                const float* __restrict__ win,
                float* __restrict__ out)
{
    __shared__ f32x2 lds[2][2][LW];   // [buf][row-of-pair][col+8] = (P, T)
    __shared__ float red[BT / 64];

    const int tid  = threadIdx.x;
    const int nrow = IMG_H / TR;             // 16
    const int img  = blockIdx.x / nrow;
    const int R0   = (blockIdx.x % nrow) * TR;

    // zero the 8-slot halos of all 4 row-slots (both buffers), once
    if (tid < 64) {
        int b = tid & 1, r = (tid >> 1) & 1, s = (tid >> 2) & 1, k = tid >> 3;
        int idx = s ? (IMG_W + 8 + k) : k;
        lds[b][r][idx] = (f32x2)(0.f, 0.f);
    }

    // exact 1-D gaussian (symmetric, 6 unique) from the passed 2-D window
    float gs[6];
    {
        float g5 = sqrtf(win[HALF * KW + HALF]);
        #pragma unroll
        for (int j = 0; j < 6; ++j) gs[j] = win[HALF * KW + j] / g5;
    }
    auto W = [&](int j) { return gs[j <= 5 ? j : 10 - j]; };  // j static

    const size_t ims = (size_t)IMG_H * IMG_W;
    // load role: 2-pixel slice (hpos) of one row of the pair, BOTH tensors
    const int hpos    = tid & 255;           // 256 float2 slices per row
    const int row_off = tid >> 8;            // row within pair (wave-uniform)
    const float* pb = pred + (size_t)img * NCH * ims + (size_t)hpos * 2;
    const float* tb = targ + (size_t)img * NCH * ims + (size_t)hpos * 2;
    const float inv3 = 1.0f / 3.0f;

    float2 p0, p1, p2, t0, t1, t2;
    auto issue = [&](int pair) {
        int r = R0 - HALF + 2 * pair + row_off;
        if (r >= 0 && r < IMG_H) {
            const float* pr = pb + (size_t)r * IMG_W;
            const float* tr = tb + (size_t)r * IMG_W;
            p0 = *(const float2*)(pr);
            p1 = *(const float2*)(pr + ims);
            p2 = *(const float2*)(pr + 2 * ims);
            t0 = *(const float2*)(tr);
            t1 = *(const float2*)(tr + ims);
            t2 = *(const float2*)(tr + 2 * ims);
        } else {
            p0 = make_float2(0.f, 0.f);
            p1 = p0; p2 = p0; t0 = p0; t1 = p0; t2 = p0;
        }
    };
    auto commit = [&](int pair) {
        float4 m;                             // {P0, T0, P1, T1}
        m.x = (p0.x + p1.x + p2.x) * inv3;
        m.y = (t0.x + t1.x + t2.x) * inv3;
        m.z = (p0.y + p1.y + p2.y) * inv3;
        m.w = (t0.y + t1.y + t2.y) * inv3;
        *(float4*)&lds[pair & 1][row_off][8 + 2 * hpos] = m;  // b128, stride-1
    };

    // 12-slot vertical ring, plane-packed (statically indexed everywhere)
    f32x2 rMU[12], rSQ[12];   // (hconv P, hconv T), (hconv P^2, hconv T^2)
    float rPT[12];            // hconv P*T
    #pragma unroll
    for (int k = 0; k < 12; ++k) {
        rMU[k] = (f32x2)(0.f, 0.f); rSQ[k] = (f32x2)(0.f, 0.f); rPT[k] = 0.f;
    }

    const float C1 = 1e-4f, C2 = 9e-4f;
    const int c = tid;                       // output column
    float acc = 0.f;

    issue(0);
    for (int i = 0; i < NP; ++i) {
        commit(i);               // vmcnt drained here, BEFORE the barrier
        __syncthreads();         // barrier sees no outstanding vmem
        if (i + 1 < NP) issue(i + 1);   // loads fly under the whole compute
        const int buf = i & 1;

        // horizontal 11-tap, even/odd split accumulators -> slots 10, 11
        #pragma unroll
        for (int rr = 0; rr < 2; ++rr) {
            const f32x2* Lr = &lds[buf][rr][c + 3];  // tap j -> col c-5+j
            f32x2 muA = (f32x2)(0.f, 0.f), muB = (f32x2)(0.f, 0.f);
            f32x2 sqA = (f32x2)(0.f, 0.f), sqB = (f32x2)(0.f, 0.f);
            float ptA = 0.f, ptB = 0.f;
            #pragma unroll
            for (int j = 0; j < KW; ++j) {
                const float w = W(j);
                f32x2 v = Lr[j];                      // ds_read_b64
                if (j & 1) {
                    muB += v * w; sqB += (v * v) * w; ptB += (v.x * v.y) * w;
                } else {
                    muA += v * w; sqA += (v * v) * w; ptA += (v.x * v.y) * w;
                }
            }
            rMU[10 + rr] = muA + muB;
            rSQ[10 + rr] = sqA + sqB;
            rPT[10 + rr] = ptA + ptB;
        }

        // vertical 11-tap + SSIM, even/odd split accumulators
        if (i >= 5) {
            #pragma unroll
            for (int off = 0; off < 2; ++off) {
                f32x2 mA = (f32x2)(0.f, 0.f), mB = (f32x2)(0.f, 0.f);
                f32x2 eA = (f32x2)(0.f, 0.f), eB = (f32x2)(0.f, 0.f);
                float pA = 0.f, pB = 0.f;
                #pragma unroll
                for (int k = 0; k < KW; ++k) {
                    const float w = W(k);
                    if (k & 1) {
                        mB += rMU[off + k] * w; eB += rSQ[off + k] * w;
                        pB += rPT[off + k] * w;
                    } else {
                        mA += rMU[off + k] * w; eA += rSQ[off + k] * w;
                        pA += rPT[off + k] * w;
                    }
                }
                f32x2 m = mA + mB, e = eA + eB;
                float ept = pA + pB;
                f32x2 msq = m * m;                    // (m11, m22)
                float m12 = m.x * m.y;
                f32x2 s = e - msq;                    // (s1, s2)
                float s12 = ept - m12;
                float num = (2.f * m12 + C1) * (2.f * s12 + C2);
                float den = (msq.x + msq.y + C1) * (s.x + s.y + C2);
                acc += 1.f - num * __builtin_amdgcn_rcpf(den);
            }
        }

        // shift ring by 2
        #pragma unroll
        for (int k = 0; k < 10; ++k) {
            rMU[k] = rMU[k + 2]; rSQ[k] = rSQ[k + 2]; rPT[k] = rPT[k + 2];
        }
    }

    // block reduction
    #pragma unroll
    for (int off = 32; off >= 1; off >>= 1)
        acc += __shfl_down(acc, off, 64);
    if ((tid & 63) == 0) red[tid >> 6] = acc;
    __syncthreads();
    if (tid == 0) {
        float s = 0.f;
        #pragma unroll
        for (int w = 0; w < BT / 64; ++w) s += red[w];
        atomicAdd(out, s * (1.0f / ((float)NB * IMG_H * IMG_W)));
    }
}

extern "C" void kernel_launch(void* const* d_in, const int* in_sizes, int n_in,
                              void* d_out, int out_size, void* d_ws, size_t ws_size,
                              hipStream_t stream) {
    const float* pred = (const float*)d_in[0];
    const float* targ = (const float*)d_in[1];
    const float* win  = (const float*)d_in[2];
    float* out = (float*)d_out;

    hipMemsetAsync(out, 0, sizeof(float), stream);

    dim3 grid(NB * (IMG_H / TR));   // 512 blocks, 8 waves each
    ssim_fused<<<grid, BT, 0, stream>>>(pred, targ, win, out);
}